// Round 3
// baseline (10901.156 us; speedup 1.0000x reference)
//
#include <hip/hip_runtime.h>
#include <math.h>

#define TL 131072

// Output layout (flat f32 element offsets into d_out):
//   recon [TL,16] @0, pred [TL,16] @TL*16, lm_pred [2,TL,8] @TL*32,
//   lv_pred [2,TL,8] @TL*48, Ct [TL,16,8] @TL*64, Ct_1 [TL,16,8] @TL*192
static constexpr size_t OFF_RECON = 0;
static constexpr size_t OFF_PRED  = (size_t)TL * 16;
static constexpr size_t OFF_LMP   = (size_t)TL * 32;
static constexpr size_t OFF_LVP   = (size_t)TL * 48;
static constexpr size_t OFF_CT    = (size_t)TL * 64;
static constexpr size_t OFF_CT1   = (size_t)TL * 192;

struct Params {
  const float* lm;  const float* lv;  const float* Tin;
  const float* cw0; const float* cb0; const float* cw1; const float* cb1; const float* cw2; const float* cb2;
  const float* pw0; const float* pb0; const float* pw1; const float* pb1; const float* pw2; const float* pb2;
  const float* fmw1; const float* fmb1; const float* fmw2; const float* fmb2;
  const float* fvw1; const float* fvb1; const float* fvw2; const float* fvb2;
  const float* lw0; const float* lb0; const float* lw1; const float* lb1; const float* lw2; const float* lb2;
  const float* w12src;   // precomputed w12/b12 in d_ws, or nullptr
  float* out;
};

__device__ __forceinline__ const float4* rc4(const float* p) { return reinterpret_cast<const float4*>(p); }
__device__ __forceinline__ float4*       rw4(float* p)       { return reinterpret_cast<float4*>(p); }

__device__ __forceinline__ void load8(const float* __restrict__ src, float* dst) {
  float4 a = rc4(src)[0], b = rc4(src)[1];
  dst[0]=a.x; dst[1]=a.y; dst[2]=a.z; dst[3]=a.w;
  dst[4]=b.x; dst[5]=b.y; dst[6]=b.z; dst[7]=b.w;
}
__device__ __forceinline__ void store8(float* __restrict__ dst, const float* v) {
  rw4(dst)[0] = make_float4(v[0],v[1],v[2],v[3]);
  rw4(dst)[1] = make_float4(v[4],v[5],v[6],v[7]);
}
__device__ __forceinline__ void store16(float* __restrict__ dst, const float* v) {
  rw4(dst)[0] = make_float4(v[0],v[1],v[2],v[3]);
  rw4(dst)[1] = make_float4(v[4],v[5],v[6],v[7]);
  rw4(dst)[2] = make_float4(v[8],v[9],v[10],v[11]);
  rw4(dst)[3] = make_float4(v[12],v[13],v[14],v[15]);
}

// ---- prep: collapse decoder layers 1+2 (linear compose; no relu between them)
__global__ __launch_bounds__(256) void tld_prep(const float* __restrict__ lw1,
                                                const float* __restrict__ lw2,
                                                const float* __restrict__ lb1,
                                                const float* __restrict__ lb2,
                                                float* __restrict__ ws) {
  const int tid = threadIdx.x;
  #pragma unroll 1
  for (int i = tid; i < 1024; i += 256) {
    int n = i >> 6, h = i & 63;
    float s = 0.f;
    #pragma unroll 8
    for (int o = 0; o < 64; ++o)
      s = fmaf(lw1[n * 4096 + h * 64 + o], lw2[n * 64 + o], s);
    ws[i] = s;
  }
  if (tid < 16) {
    float b = lb2[tid];
    #pragma unroll 8
    for (int o = 0; o < 64; ++o)
      b = fmaf(lb1[tid * 64 + o], lw2[tid * 64 + o], b);
    ws[1024 + tid] = b;
  }
}

__global__ __launch_bounds__(256, 2) void tld_fused(Params p) {
  __shared__ __align__(16) float s_w12[16 * 64];    // 4KB
  __shared__ __align__(16) float s_b12[16];
  __shared__ __align__(16) float s_lb0[16 * 64];    // 4KB
  __shared__ __align__(16) float s_ew2[2][1024];    // 8KB  (cw2, pw2)
  __shared__ __align__(16) float s_eb2[2][128];     // 1KB
  __shared__ __align__(16) float s_hw1t[2][1024];   // 8KB  transposed [o][f]
  __shared__ __align__(16) float s_hw2[2][1024];    // 8KB  [o][j]
  __shared__ __align__(16) float s_hb1[2][128];     // 1KB
  __shared__ __align__(16) float s_hb2[2][8];
  __shared__ __align__(16) float s_lw0[2][2048];    // 16KB ping-pong

  const int tid = threadIdx.x;

  // ================= block staging =================
  rw4(s_ew2[0])[tid] = rc4(p.cw2)[tid];     // 1024 f32 = 256 f4
  rw4(s_ew2[1])[tid] = rc4(p.pw2)[tid];
  rw4(s_lb0)[tid]    = rc4(p.lb0)[tid];
  rw4(s_hw2[0])[tid] = rc4(p.fmw2)[tid];
  rw4(s_hw2[1])[tid] = rc4(p.fvw2)[tid];
  if (tid < 32)        { rw4(s_hb1[0])[tid] = rc4(p.fmb1)[tid]; rw4(s_eb2[0])[tid] = rc4(p.cb2)[tid]; }
  else if (tid < 64)   { int q = tid - 32; rw4(s_hb1[1])[q] = rc4(p.fvb1)[q]; rw4(s_eb2[1])[q] = rc4(p.pb2)[q]; }
  else if (tid < 68)   { int q = tid - 64; int r = q >> 1, h = q & 1;
                         rw4(s_hb2[r])[h] = rc4(r ? p.fvb2 : p.fmb2)[h]; }
  #pragma unroll 1
  for (int i = tid; i < 1024; i += 256) {   // transpose head W1 -> [o][f]
    int o = i >> 3, f = i & 7;
    s_hw1t[0][i] = p.fmw1[f * 128 + o];
    s_hw1t[1][i] = p.fvw1[f * 128 + o];
  }
  rw4(s_lw0[0])[tid * 2]     = rc4(p.lw0)[tid * 2];   // node 0
  rw4(s_lw0[0])[tid * 2 + 1] = rc4(p.lw0)[tid * 2 + 1];
  if (p.w12src) {
    rw4(s_w12)[tid] = rc4(p.w12src)[tid];
    if (tid < 4) rw4(s_b12)[tid] = rc4(p.w12src + 1024)[tid];
  } else {
    #pragma unroll 1
    for (int i = tid; i < 1024; i += 256) {
      int n = i >> 6, h = i & 63;
      float s = 0.f;
      for (int o = 0; o < 64; ++o)
        s = fmaf(p.lw1[n * 4096 + h * 64 + o], p.lw2[n * 64 + o], s);
      s_w12[i] = s;
    }
    if (tid < 16) {
      float b = p.lb2[tid];
      for (int o = 0; o < 64; ++o)
        b = fmaf(p.lb1[tid * 64 + o], p.lw2[tid * 64 + o], b);
      s_b12[tid] = b;
    }
  }
  __syncthreads();

  // ================= per-thread mapping (TPT=2) =================
  const int wv   = tid >> 6;
  const int role = __builtin_amdgcn_readfirstlane(wv >> 1);  // waves 0-1: role0, 2-3: role1
  const int wpr  = wv & 1;
  const int lane = tid & 63;
  const int tA = blockIdx.x * 256 + wpr * 64 + lane;
  const int tB = tA + 128;
  const float TtA = p.Tin[tA], TtB = p.Tin[tB];

  float dl[2][4][8];                 // [t][{lm0,lm1,lv0,lv1}][k] decode latents
  unsigned long long cmlo[2], cmhi[2];
  float e1f[2][8];

  // ================= encoder prologue + C stores (tight bursts) =================
  if (role == 0) {
    // f64 path: <0.1 binarization must match f64-resolved reference (round-1 fail)
    double e1d[2][8];
    #pragma unroll
    for (int tt = 0; tt < 2; ++tt) {
      const double Td = (double)(tt ? TtB : TtA);
      double e0d[8];
      #pragma unroll
      for (int j = 0; j < 8; ++j) {
        double v = Td * (double)p.cw0[j] + (double)p.cb0[j];
        e0d[j] = v < 0.0 ? 0.01 * v : v;
      }
      #pragma unroll
      for (int j = 0; j < 8; ++j) {
        double v = (double)p.cb1[j];
        #pragma unroll
        for (int i = 0; i < 8; ++i) v = fma(e0d[i], (double)p.cw1[i * 8 + j], v);
        e1d[tt][j] = v < 0.0 ? 0.01 * v : v;
      }
      cmlo[tt] = 0ull; cmhi[tt] = 0ull;
    }
    #pragma unroll 1
    for (int n = 0; n < 16; ++n) {
      float cbA[8], cbB[8];
      #pragma unroll
      for (int k = 0; k < 8; ++k) {
        double s0 = (double)s_eb2[0][n * 8 + k];
        double s1 = s0;
        #pragma unroll
        for (int i = 0; i < 8; ++i) {
          const double w = (double)s_ew2[0][i * 128 + n * 8 + k];
          s0 = fma(e1d[0][i], w, s0);
          s1 = fma(e1d[1][i], w, s1);
        }
        const int b0 = (s0 < 0.1) ? 0 : 1;
        const int b1 = (s1 < 0.1) ? 0 : 1;
        cbA[k] = (float)b0; cbB[k] = (float)b1;
        const int sh = (n * 8 + k) & 63;
        if (n < 8) { cmlo[0] |= (unsigned long long)b0 << sh; cmlo[1] |= (unsigned long long)b1 << sh; }
        else       { cmhi[0] |= (unsigned long long)b0 << sh; cmhi[1] |= (unsigned long long)b1 << sh; }
      }
      store8(p.out + OFF_CT + (size_t)tA * 128 + n * 8, cbA);
      store8(p.out + OFF_CT + (size_t)tB * 128 + n * 8, cbB);
    }
  } else {
    #pragma unroll
    for (int tt = 0; tt < 2; ++tt) {
      const float Tt = tt ? TtB : TtA;
      float e0[8];
      #pragma unroll
      for (int j = 0; j < 8; ++j) {
        float v = fmaf(Tt, p.pw0[j], p.pb0[j]);
        e0[j] = v < 0.f ? 0.01f * v : v;
      }
      #pragma unroll
      for (int j = 0; j < 8; ++j) {
        float v = p.pb1[j];
        #pragma unroll
        for (int i = 0; i < 8; ++i) v = fmaf(e0[i], p.pw1[i * 8 + j], v);
        e1f[tt][j] = v < 0.f ? 0.01f * v : v;
      }
    }
    #pragma unroll 1
    for (int n = 0; n < 16; ++n) {
      float cbA[8], cbB[8];
      #pragma unroll
      for (int k = 0; k < 8; ++k) {
        float s0 = s_eb2[1][n * 8 + k], s1 = s0;
        #pragma unroll
        for (int i = 0; i < 8; ++i) {
          const float w = s_ew2[1][i * 128 + n * 8 + k];
          s0 = fmaf(e1f[0][i], w, s0);
          s1 = fmaf(e1f[1][i], w, s1);
        }
        cbA[k] = s0; cbB[k] = s1;
      }
      store8(p.out + OFF_CT1 + (size_t)tA * 128 + n * 8, cbA);
      store8(p.out + OFF_CT1 + (size_t)tB * 128 + n * 8, cbB);
    }
  }

  // ================= latent loads =================
  if (role == 0) {
    #pragma unroll
    for (int tt = 0; tt < 2; ++tt) {
      const int t = tt ? tB : tA;
      load8(p.lm + (size_t)t * 8, dl[tt][0]);
      load8(p.lm + (size_t)TL * 8 + (size_t)t * 8, dl[tt][1]);
      load8(p.lv + (size_t)t * 8, dl[tt][2]);
      load8(p.lv + (size_t)TL * 8 + (size_t)t * 8, dl[tt][3]);
    }
  } else {
    #pragma unroll
    for (int tt = 0; tt < 2; ++tt) {
      const int t = tt ? tB : tA;
      if (t > 0) {
        load8(p.lm + (size_t)(t - 1) * 8, dl[tt][0]);
        load8(p.lm + (size_t)TL * 8 + (size_t)(t - 1) * 8, dl[tt][1]);
        load8(p.lv + (size_t)(t - 1) * 8, dl[tt][2]);
        load8(p.lv + (size_t)TL * 8 + (size_t)(t - 1) * 8, dl[tt][3]);
      } else {
        #pragma unroll
        for (int j = 0; j < 8; ++j) { dl[tt][0][j]=0.f; dl[tt][1][j]=0.f; dl[tt][2][j]=0.f; dl[tt][3][j]=0.f; }
      }
    }
  }

  // ================= heads (weights shared across 2t x 2l) =================
  {
    float hx[2][2][8];
    if (role == 0) {
      #pragma unroll
      for (int tt = 0; tt < 2; ++tt)
        #pragma unroll
        for (int j = 0; j < 8; ++j) { hx[tt][0][j] = dl[tt][0][j]; hx[tt][1][j] = dl[tt][1][j]; }
    } else {
      #pragma unroll
      for (int tt = 0; tt < 2; ++tt) {
        const int t = tt ? tB : tA;
        load8(p.lv + (size_t)t * 8, hx[tt][0]);
        load8(p.lv + (size_t)TL * 8 + (size_t)t * 8, hx[tt][1]);
      }
    }
    float acc8[2][2][8];
    #pragma unroll
    for (int tt = 0; tt < 2; ++tt)
      #pragma unroll
      for (int l = 0; l < 2; ++l)
        #pragma unroll
        for (int j = 0; j < 8; ++j) acc8[tt][l][j] = s_hb2[role][j];
    const float* w1t = s_hw1t[role];
    const float* w2r = s_hw2[role];
    const float* b1  = s_hb1[role];
    #pragma unroll 1
    for (int o = 0; o < 128; ++o) {
      float4 u0 = rc4(w1t)[o * 2], u1 = rc4(w1t)[o * 2 + 1];
      const float wf[8] = {u0.x,u0.y,u0.z,u0.w,u1.x,u1.y,u1.z,u1.w};
      const float bo = b1[o];
      float av[2][2];
      #pragma unroll
      for (int tt = 0; tt < 2; ++tt)
        #pragma unroll
        for (int l = 0; l < 2; ++l) {
          float a = bo;
          #pragma unroll
          for (int f = 0; f < 8; ++f) a = fmaf(hx[tt][l][f], wf[f], a);
          av[tt][l] = fmaxf(a, 0.f);
        }
      float4 v0 = rc4(w2r)[o * 2], v1 = rc4(w2r)[o * 2 + 1];
      const float w2f[8] = {v0.x,v0.y,v0.z,v0.w,v1.x,v1.y,v1.z,v1.w};
      #pragma unroll
      for (int tt = 0; tt < 2; ++tt)
        #pragma unroll
        for (int l = 0; l < 2; ++l)
          #pragma unroll
          for (int j = 0; j < 8; ++j)
            acc8[tt][l][j] = fmaf(av[tt][l], w2f[j], acc8[tt][l][j]);
    }
    const size_t hbase = role ? OFF_LVP : OFF_LMP;
    #pragma unroll
    for (int tt = 0; tt < 2; ++tt) {
      const int t = tt ? tB : tA;
      store8(p.out + hbase + (size_t)t * 8, acc8[tt][0]);
      store8(p.out + hbase + (size_t)TL * 8 + (size_t)t * 8, acc8[tt][1]);
    }
  }

  // ================= decode node loop (LDS ping-pong, T14 reg prefetch) =================
  float rrA[16], rrB[16];
  #pragma unroll
  for (int q = 0; q < 16; ++q) { rrA[q] = 0.f; rrB[q] = 0.f; }

  #pragma unroll 1
  for (int n = 0; n < 16; ++n) {
    float4 pf0, pf1;
    if (n < 15) {                       // issue next node's weights early (T14)
      const float4* g = rc4(p.lw0 + (size_t)(n + 1) * 2048);
      pf0 = g[tid * 2]; pf1 = g[tid * 2 + 1];
    }
    // c values for this node
    float cc[2][8];
    unsigned km;
    if (role == 0) {
      #pragma unroll
      for (int tt = 0; tt < 2; ++tt) {
        const unsigned long long mw = (n < 8) ? cmlo[tt] : cmhi[tt];
        const unsigned w8 = (unsigned)(mw >> ((n * 8) & 63)) & 0xffu;
        #pragma unroll
        for (int k = 0; k < 8; ++k) cc[tt][k] = ((w8 >> k) & 1u) ? 1.f : 0.f;
      }
      km = 0u;
      #pragma unroll
      for (int k = 0; k < 8; ++k) {
        const int nz = (cc[0][k] + cc[1][k]) != 0.f;
        km |= (__ballot(nz) ? 1u : 0u) << k;
      }
    } else {
      #pragma unroll
      for (int k = 0; k < 8; ++k) {
        float s0 = s_eb2[1][n * 8 + k], s1 = s0;
        #pragma unroll
        for (int i = 0; i < 8; ++i) {
          const float w = s_ew2[1][i * 128 + n * 8 + k];
          s0 = fmaf(e1f[0][i], w, s0);
          s1 = fmaf(e1f[1][i], w, s1);
        }
        cc[0][k] = s0; cc[1][k] = s1;
      }
      km = 0xffu;
    }

    const float* Wb = s_lw0[n & 1];
    float s0 = s_b12[n], s1 = s_b12[n];
    #pragma unroll 1
    for (int ob = 0; ob < 64; ob += 16) {
      float a0[16], a1[16];
      #pragma unroll
      for (int j4 = 0; j4 < 4; ++j4) {
        float4 b = rc4(s_lb0 + n * 64 + ob)[j4];
        a0[j4*4+0]=b.x; a0[j4*4+1]=b.y; a0[j4*4+2]=b.z; a0[j4*4+3]=b.w;
        a1[j4*4+0]=b.x; a1[j4*4+1]=b.y; a1[j4*4+2]=b.z; a1[j4*4+3]=b.w;
      }
      #pragma unroll
      for (int k = 0; k < 8; ++k) {
        if (km & (1u << k)) {
          #pragma unroll
          for (int r4 = 0; r4 < 4; ++r4) {
            const int row = (r4 < 2) ? (2 * k + r4) : (14 + 2 * k + r4);
            const float xA = cc[0][k] * dl[0][r4][k];
            const float xB = cc[1][k] * dl[1][r4][k];
            const float4* wr = rc4(Wb + row * 64 + ob);
            #pragma unroll
            for (int j4 = 0; j4 < 4; ++j4) {
              const float4 w = wr[j4];
              a0[j4*4+0] = fmaf(xA, w.x, a0[j4*4+0]); a1[j4*4+0] = fmaf(xB, w.x, a1[j4*4+0]);
              a0[j4*4+1] = fmaf(xA, w.y, a0[j4*4+1]); a1[j4*4+1] = fmaf(xB, w.y, a1[j4*4+1]);
              a0[j4*4+2] = fmaf(xA, w.z, a0[j4*4+2]); a1[j4*4+2] = fmaf(xB, w.z, a1[j4*4+2]);
              a0[j4*4+3] = fmaf(xA, w.w, a0[j4*4+3]); a1[j4*4+3] = fmaf(xB, w.w, a1[j4*4+3]);
            }
          }
        }
      }
      #pragma unroll
      for (int j = 0; j < 16; ++j) {
        const float wj = s_w12[n * 64 + ob + j];
        s0 = fmaf(fmaxf(a0[j], 0.f), wj, s0);
        s1 = fmaf(fmaxf(a1[j], 0.f), wj, s1);
      }
    }
    const float v0 = fmaxf(s0, 0.f), v1 = fmaxf(s1, 0.f);
    #pragma unroll
    for (int q = 0; q < 16; ++q) {      // predicated static-index update (rule 20)
      rrA[q] = (n == q) ? v0 : rrA[q];
      rrB[q] = (n == q) ? v1 : rrB[q];
    }
    if (n < 15) {
      rw4(s_lw0[(n + 1) & 1])[tid * 2]     = pf0;
      rw4(s_lw0[(n + 1) & 1])[tid * 2 + 1] = pf1;
    }
    __syncthreads();
  }

  const size_t r_off = role ? OFF_PRED : OFF_RECON;
  store16(p.out + r_off + (size_t)tA * 16, rrA);
  store16(p.out + r_off + (size_t)tB * 16, rrB);
}

extern "C" void kernel_launch(void* const* d_in, const int* in_sizes, int n_in,
                              void* d_out, int out_size, void* d_ws, size_t ws_size,
                              hipStream_t stream) {
  Params p;
  p.lm   = (const float*)d_in[0];
  p.lv   = (const float*)d_in[1];
  p.Tin  = (const float*)d_in[2];
  p.cw0  = (const float*)d_in[3];  p.cb0 = (const float*)d_in[4];
  p.cw1  = (const float*)d_in[5];  p.cb1 = (const float*)d_in[6];
  p.cw2  = (const float*)d_in[7];  p.cb2 = (const float*)d_in[8];
  p.pw0  = (const float*)d_in[9];  p.pb0 = (const float*)d_in[10];
  p.pw1  = (const float*)d_in[11]; p.pb1 = (const float*)d_in[12];
  p.pw2  = (const float*)d_in[13]; p.pb2 = (const float*)d_in[14];
  p.fmw1 = (const float*)d_in[15]; p.fmb1 = (const float*)d_in[16];
  p.fmw2 = (const float*)d_in[17]; p.fmb2 = (const float*)d_in[18];
  p.fvw1 = (const float*)d_in[19]; p.fvb1 = (const float*)d_in[20];
  p.fvw2 = (const float*)d_in[21]; p.fvb2 = (const float*)d_in[22];
  p.lw0  = (const float*)d_in[23]; p.lb0 = (const float*)d_in[24];
  p.lw1  = (const float*)d_in[25]; p.lb1 = (const float*)d_in[26];
  p.lw2  = (const float*)d_in[27]; p.lb2 = (const float*)d_in[28];
  p.out  = (float*)d_out;

  const bool use_ws = ws_size >= 1040 * sizeof(float);
  if (use_ws) {
    tld_prep<<<dim3(1), dim3(256), 0, stream>>>(p.lw1, p.lw2, p.lb1, p.lb2, (float*)d_ws);
    p.w12src = (const float*)d_ws;
  } else {
    p.w12src = nullptr;
  }
  tld_fused<<<dim3(TL / 256), dim3(256), 0, stream>>>(p);
}

// Round 4
// 639.965 us; speedup vs baseline: 17.0340x; 17.0340x over previous
//
#include <hip/hip_runtime.h>
#include <math.h>

#define TL 131072

// Output layout (flat f32 element offsets into d_out):
//   recon [TL,16] @0, pred [TL,16] @TL*16, lm_pred [2,TL,8] @TL*32,
//   lv_pred [2,TL,8] @TL*48, Ct [TL,16,8] @TL*64, Ct_1 [TL,16,8] @TL*192
static constexpr size_t OFF_RECON = 0;
static constexpr size_t OFF_PRED  = (size_t)TL * 16;
static constexpr size_t OFF_LMP   = (size_t)TL * 32;
static constexpr size_t OFF_LVP   = (size_t)TL * 48;
static constexpr size_t OFF_CT    = (size_t)TL * 64;
static constexpr size_t OFF_CT1   = (size_t)TL * 192;

struct Params {
  const float* lm;  const float* lv;  const float* Tin;
  const float* cw0; const float* cb0; const float* cw1; const float* cb1; const float* cw2; const float* cb2;
  const float* pw0; const float* pb0; const float* pw1; const float* pb1; const float* pw2; const float* pb2;
  const float* fmw1; const float* fmb1; const float* fmw2; const float* fmb2;
  const float* fvw1; const float* fvb1; const float* fvw2; const float* fvb2;
  const float* lw0; const float* lb0; const float* lw1; const float* lb1; const float* lw2; const float* lb2;
  const float* w12src;   // precomputed w12/b12 in d_ws, or nullptr
  float* out;
};

__device__ __forceinline__ const float4* rc4(const float* p) { return reinterpret_cast<const float4*>(p); }
__device__ __forceinline__ float4*       rw4(float* p)       { return reinterpret_cast<float4*>(p); }

__device__ __forceinline__ void load8(const float* __restrict__ src, float* dst) {
  float4 a = rc4(src)[0], b = rc4(src)[1];
  dst[0]=a.x; dst[1]=a.y; dst[2]=a.z; dst[3]=a.w;
  dst[4]=b.x; dst[5]=b.y; dst[6]=b.z; dst[7]=b.w;
}
__device__ __forceinline__ void store8(float* __restrict__ dst, const float* v) {
  rw4(dst)[0] = make_float4(v[0],v[1],v[2],v[3]);
  rw4(dst)[1] = make_float4(v[4],v[5],v[6],v[7]);
}
__device__ __forceinline__ void store16(float* __restrict__ dst, const float* v) {
  rw4(dst)[0] = make_float4(v[0],v[1],v[2],v[3]);
  rw4(dst)[1] = make_float4(v[4],v[5],v[6],v[7]);
  rw4(dst)[2] = make_float4(v[8],v[9],v[10],v[11]);
  rw4(dst)[3] = make_float4(v[12],v[13],v[14],v[15]);
}

// ---- prep: collapse decoder layers 1+2 (linear compose; no relu between them)
__global__ __launch_bounds__(256) void tld_prep(const float* __restrict__ lw1,
                                                const float* __restrict__ lw2,
                                                const float* __restrict__ lb1,
                                                const float* __restrict__ lb2,
                                                float* __restrict__ ws) {
  const int tid = threadIdx.x;
  #pragma unroll 1
  for (int i = tid; i < 1024; i += 256) {
    int n = i >> 6, h = i & 63;
    float s = 0.f;
    #pragma unroll 8
    for (int o = 0; o < 64; ++o)
      s = fmaf(lw1[n * 4096 + h * 64 + o], lw2[n * 64 + o], s);
    ws[i] = s;
  }
  if (tid < 16) {
    float b = lb2[tid];
    #pragma unroll 8
    for (int o = 0; o < 64; ++o)
      b = fmaf(lb1[tid * 64 + o], lw2[tid * 64 + o], b);
    ws[1024 + tid] = b;
  }
}

__global__ __launch_bounds__(256, 4) void tld_fused(Params p) {
  // 38.5 KB total -> 4 blocks/CU; grid 1024 = fully resident
  __shared__ __align__(16) float s_lw0[2048];     // 8KB  single buffer, per-node
  __shared__ __align__(16) float s_w12[1024];     // 4KB
  __shared__ __align__(16) float s_b12[16];
  __shared__ __align__(16) float s_lb0[1024];     // 4KB
  __shared__ __align__(16) float s_ew2b[1024];    // 4KB  pw2 (role1 c-weights)
  __shared__ __align__(16) float s_eb2b[128];     // pb2
  __shared__ __align__(16) float s_hw1t[2][1024]; // 8KB  head W1 transposed [o][f]
  __shared__ __align__(16) float s_hw2[2][1024];  // 8KB  head W2 [o][j]
  __shared__ __align__(16) float s_hb1[2][128];   // 1KB
  __shared__ __align__(16) float s_hb2[2][8];

  const int tid = threadIdx.x;

  // ================= block staging =================
  rw4(s_lb0)[tid]    = rc4(p.lb0)[tid];
  rw4(s_ew2b)[tid]   = rc4(p.pw2)[tid];
  rw4(s_hw2[0])[tid] = rc4(p.fmw2)[tid];
  rw4(s_hw2[1])[tid] = rc4(p.fvw2)[tid];
  if (tid < 32)       { rw4(s_hb1[0])[tid] = rc4(p.fmb1)[tid]; }
  else if (tid < 64)  { rw4(s_hb1[1])[tid - 32] = rc4(p.fvb1)[tid - 32]; }
  else if (tid < 96)  { rw4(s_eb2b)[tid - 64] = rc4(p.pb2)[tid - 64]; }
  else if (tid < 100) { int q = tid - 96; rw4(s_hb2[q >> 1])[q & 1] = rc4((q >> 1) ? p.fvb2 : p.fmb2)[q & 1]; }
  #pragma unroll 1
  for (int i = tid; i < 2048; i += 256) {  // transpose head W1 -> [o][f]
    int r = i >> 10, ii = i & 1023, o = ii >> 3, f = ii & 7;
    s_hw1t[r][ii] = (r ? p.fvw1 : p.fmw1)[f * 128 + o];
  }
  rw4(s_lw0)[tid * 2]     = rc4(p.lw0)[tid * 2];   // node 0
  rw4(s_lw0)[tid * 2 + 1] = rc4(p.lw0)[tid * 2 + 1];
  if (p.w12src) {
    rw4(s_w12)[tid] = rc4(p.w12src)[tid];
    if (tid < 4) rw4(s_b12)[tid] = rc4(p.w12src + 1024)[tid];
  } else {
    #pragma unroll 1
    for (int i = tid; i < 1024; i += 256) {
      int n = i >> 6, h = i & 63;
      float s = 0.f;
      for (int o = 0; o < 64; ++o)
        s = fmaf(p.lw1[n * 4096 + h * 64 + o], p.lw2[n * 64 + o], s);
      s_w12[i] = s;
    }
    if (tid < 16) {
      float b = p.lb2[tid];
      for (int o = 0; o < 64; ++o)
        b = fmaf(p.lb1[tid * 64 + o], p.lw2[tid * 64 + o], b);
      s_b12[tid] = b;
    }
  }
  __syncthreads();

  // ================= mapping (TPT=1, round-2 style) =================
  const int t    = blockIdx.x * 128 + (tid & 127);
  const int role = __builtin_amdgcn_readfirstlane((int)(tid >> 7));
  const float Tt = p.Tin[t];

  unsigned long long cmlo = 0ull, cmhi = 0ull;   // role0: 128 Ct bits
  float e1f[8];                                  // role1: encoder hidden

  // ================= encoder prologue =================
  if (role == 0) {
    // f64 path: the <0.1 binarization must match the f64-resolved reference
    // (round-1 failure: f32 fma noise flips knife-edge elements).
    double e0d[8], e1d[8];
    const double Td = (double)Tt;
    #pragma unroll
    for (int j = 0; j < 8; ++j) {
      double v = Td * (double)p.cw0[j] + (double)p.cb0[j];
      e0d[j] = v < 0.0 ? 0.01 * v : v;
    }
    #pragma unroll
    for (int j = 0; j < 8; ++j) {
      double v = (double)p.cb1[j];
      #pragma unroll
      for (int i = 0; i < 8; ++i) v = fma(e0d[i], (double)p.cw1[i * 8 + j], v);
      e1d[j] = v < 0.0 ? 0.01 * v : v;
    }
    #pragma unroll 1
    for (int n = 0; n < 16; ++n) {
      float cb[8];
      #pragma unroll
      for (int k = 0; k < 8; ++k) {
        double s = (double)p.cb2[n * 8 + k];
        #pragma unroll
        for (int i = 0; i < 8; ++i)
          s = fma(e1d[i], (double)p.cw2[i * 128 + n * 8 + k], s);
        const int b = (s < 0.1) ? 0 : 1;
        cb[k] = (float)b;
        const int idx = n * 8 + k;
        if (n < 8) cmlo |= (unsigned long long)b << (idx & 63);
        else       cmhi |= (unsigned long long)b << (idx & 63);
      }
      store8(p.out + OFF_CT + (size_t)t * 128 + n * 8, cb);
    }
  } else {
    float e0[8];
    #pragma unroll
    for (int j = 0; j < 8; ++j) {
      float v = fmaf(Tt, p.pw0[j], p.pb0[j]);
      e0[j] = v < 0.f ? 0.01f * v : v;
    }
    #pragma unroll
    for (int j = 0; j < 8; ++j) {
      float v = p.pb1[j];
      #pragma unroll
      for (int i = 0; i < 8; ++i) v = fmaf(e0[i], p.pw1[i * 8 + j], v);
      e1f[j] = v < 0.f ? 0.01f * v : v;
    }
  }

  // ================= latent loads =================
  float dl[4][8];   // {lm0,lm1,lv0,lv1} decode inputs
  if (role == 0) {
    load8(p.lm + (size_t)t * 8, dl[0]);
    load8(p.lm + (size_t)TL * 8 + (size_t)t * 8, dl[1]);
    load8(p.lv + (size_t)t * 8, dl[2]);
    load8(p.lv + (size_t)TL * 8 + (size_t)t * 8, dl[3]);
  } else {
    if (t > 0) {
      load8(p.lm + (size_t)(t - 1) * 8, dl[0]);
      load8(p.lm + (size_t)TL * 8 + (size_t)(t - 1) * 8, dl[1]);
      load8(p.lv + (size_t)(t - 1) * 8, dl[2]);
      load8(p.lv + (size_t)TL * 8 + (size_t)(t - 1) * 8, dl[3]);
    } else {
      #pragma unroll
      for (int r = 0; r < 4; ++r)
        #pragma unroll
        for (int j = 0; j < 8; ++j) dl[r][j] = 0.f;
    }
  }

  // ================= heads (LDS weights, shared across 2 layers) =================
  {
    float hx[2][8];
    if (role == 0) {
      #pragma unroll
      for (int j = 0; j < 8; ++j) { hx[0][j] = dl[0][j]; hx[1][j] = dl[1][j]; }
    } else {
      load8(p.lv + (size_t)t * 8, hx[0]);
      load8(p.lv + (size_t)TL * 8 + (size_t)t * 8, hx[1]);
    }
    float acc8[2][8];
    #pragma unroll
    for (int l = 0; l < 2; ++l)
      #pragma unroll
      for (int j = 0; j < 8; ++j) acc8[l][j] = s_hb2[role][j];
    const float* w1t = s_hw1t[role];
    const float* w2r = s_hw2[role];
    const float* b1  = s_hb1[role];
    #pragma unroll 1
    for (int o = 0; o < 128; ++o) {
      float4 u0 = rc4(w1t)[o * 2], u1 = rc4(w1t)[o * 2 + 1];
      const float wf[8] = {u0.x,u0.y,u0.z,u0.w,u1.x,u1.y,u1.z,u1.w};
      const float bo = b1[o];
      float a0 = bo, a1 = bo;
      #pragma unroll
      for (int f = 0; f < 8; ++f) {
        a0 = fmaf(hx[0][f], wf[f], a0);
        a1 = fmaf(hx[1][f], wf[f], a1);
      }
      a0 = fmaxf(a0, 0.f); a1 = fmaxf(a1, 0.f);
      float4 v0 = rc4(w2r)[o * 2], v1 = rc4(w2r)[o * 2 + 1];
      const float w2f[8] = {v0.x,v0.y,v0.z,v0.w,v1.x,v1.y,v1.z,v1.w};
      #pragma unroll
      for (int j = 0; j < 8; ++j) {
        acc8[0][j] = fmaf(a0, w2f[j], acc8[0][j]);
        acc8[1][j] = fmaf(a1, w2f[j], acc8[1][j]);
      }
    }
    const size_t hbase = role ? OFF_LVP : OFF_LMP;
    store8(p.out + hbase + (size_t)t * 8, acc8[0]);
    store8(p.out + hbase + (size_t)TL * 8 + (size_t)t * 8, acc8[1]);
  }

  // ================= decode node loop (LDS single buffer + reg prefetch) =================
  float rr[16];
  #pragma unroll
  for (int q = 0; q < 16; ++q) rr[q] = 0.f;

  #pragma unroll 1
  for (int n = 0; n < 16; ++n) {
    float4 pf0, pf1;
    if (n < 15) {                        // issue next node's weights early (T14)
      const float4* g = rc4(p.lw0 + (size_t)(n + 1) * 2048);
      pf0 = g[tid * 2]; pf1 = g[tid * 2 + 1];
    }
    float cc[8];
    if (role == 0) {
      const unsigned long long mw = (n < 8) ? cmlo : cmhi;
      const unsigned w8 = (unsigned)(mw >> ((n * 8) & 63)) & 0xffu;
      #pragma unroll
      for (int k = 0; k < 8; ++k) cc[k] = (float)((w8 >> k) & 1u);
    } else {
      #pragma unroll
      for (int k = 0; k < 8; ++k) {
        float s0 = s_eb2b[n * 8 + k];
        #pragma unroll
        for (int i = 0; i < 8; ++i)
          s0 = fmaf(e1f[i], s_ew2b[i * 128 + n * 8 + k], s0);
        cc[k] = s0;
      }
      store8(p.out + OFF_CT1 + (size_t)t * 128 + n * 8, cc);
    }

    float ssum = s_b12[n];
    #pragma unroll 1
    for (int ob = 0; ob < 64; ob += 16) {
      float a[16];
      #pragma unroll
      for (int j4 = 0; j4 < 4; ++j4) {
        float4 b = rc4(s_lb0 + n * 64 + ob)[j4];
        a[j4*4+0]=b.x; a[j4*4+1]=b.y; a[j4*4+2]=b.z; a[j4*4+3]=b.w;
      }
      #pragma unroll
      for (int k = 0; k < 8; ++k) {
        #pragma unroll
        for (int r4 = 0; r4 < 4; ++r4) {
          const int row = (r4 < 2) ? (2 * k + r4) : (14 + 2 * k + r4);
          const float xv = cc[k] * dl[r4][k];
          const float4* wr = rc4(s_lw0 + row * 64 + ob);
          #pragma unroll
          for (int j4 = 0; j4 < 4; ++j4) {
            const float4 w = wr[j4];
            a[j4*4+0] = fmaf(xv, w.x, a[j4*4+0]);
            a[j4*4+1] = fmaf(xv, w.y, a[j4*4+1]);
            a[j4*4+2] = fmaf(xv, w.z, a[j4*4+2]);
            a[j4*4+3] = fmaf(xv, w.w, a[j4*4+3]);
          }
        }
      }
      #pragma unroll
      for (int j = 0; j < 16; ++j)
        ssum = fmaf(fmaxf(a[j], 0.f), s_w12[n * 64 + ob + j], ssum);
    }
    const float v = fmaxf(ssum, 0.f);
    #pragma unroll
    for (int q = 0; q < 16; ++q)        // predicated static-index update (rule 20)
      rr[q] = (n == q) ? v : rr[q];

    __syncthreads();                     // all waves done reading s_lw0
    if (n < 15) {
      rw4(s_lw0)[tid * 2]     = pf0;     // waits vmcnt for pf implicitly
      rw4(s_lw0)[tid * 2 + 1] = pf1;
    }
    __syncthreads();                     // new weights visible
  }

  const size_t r_off = role ? OFF_PRED : OFF_RECON;
  store16(p.out + r_off + (size_t)t * 16, rr);
}

extern "C" void kernel_launch(void* const* d_in, const int* in_sizes, int n_in,
                              void* d_out, int out_size, void* d_ws, size_t ws_size,
                              hipStream_t stream) {
  Params p;
  p.lm   = (const float*)d_in[0];
  p.lv   = (const float*)d_in[1];
  p.Tin  = (const float*)d_in[2];
  p.cw0  = (const float*)d_in[3];  p.cb0 = (const float*)d_in[4];
  p.cw1  = (const float*)d_in[5];  p.cb1 = (const float*)d_in[6];
  p.cw2  = (const float*)d_in[7];  p.cb2 = (const float*)d_in[8];
  p.pw0  = (const float*)d_in[9];  p.pb0 = (const float*)d_in[10];
  p.pw1  = (const float*)d_in[11]; p.pb1 = (const float*)d_in[12];
  p.pw2  = (const float*)d_in[13]; p.pb2 = (const float*)d_in[14];
  p.fmw1 = (const float*)d_in[15]; p.fmb1 = (const float*)d_in[16];
  p.fmw2 = (const float*)d_in[17]; p.fmb2 = (const float*)d_in[18];
  p.fvw1 = (const float*)d_in[19]; p.fvb1 = (const float*)d_in[20];
  p.fvw2 = (const float*)d_in[21]; p.fvb2 = (const float*)d_in[22];
  p.lw0  = (const float*)d_in[23]; p.lb0 = (const float*)d_in[24];
  p.lw1  = (const float*)d_in[25]; p.lb1 = (const float*)d_in[26];
  p.lw2  = (const float*)d_in[27]; p.lb2 = (const float*)d_in[28];
  p.out  = (float*)d_out;

  const bool use_ws = ws_size >= 1040 * sizeof(float);
  if (use_ws) {
    tld_prep<<<dim3(1), dim3(256), 0, stream>>>(p.lw1, p.lw2, p.lb1, p.lb2, (float*)d_ws);
    p.w12src = (const float*)d_ws;
  } else {
    p.w12src = nullptr;
  }
  tld_fused<<<dim3(TL / 128), dim3(256), 0, stream>>>(p);
}

// Round 5
// 466.788 us; speedup vs baseline: 23.3536x; 1.3710x over previous
//
#include <hip/hip_runtime.h>
#include <math.h>

#define TL 131072

// Output layout (flat f32 element offsets into d_out):
//   recon [TL,16] @0, pred [TL,16] @TL*16, lm_pred [2,TL,8] @TL*32,
//   lv_pred [2,TL,8] @TL*48, Ct [TL,16,8] @TL*64, Ct_1 [TL,16,8] @TL*192
static constexpr size_t OFF_RECON = 0;
static constexpr size_t OFF_PRED  = (size_t)TL * 16;
static constexpr size_t OFF_LMP   = (size_t)TL * 32;
static constexpr size_t OFF_LVP   = (size_t)TL * 48;
static constexpr size_t OFF_CT    = (size_t)TL * 64;
static constexpr size_t OFF_CT1   = (size_t)TL * 192;

typedef _Float16 h2 __attribute__((ext_vector_type(2)));
typedef _Float16 h8 __attribute__((ext_vector_type(8)));
typedef float f32x4 __attribute__((ext_vector_type(4)));

struct Params {
  const float* lm;  const float* lv;  const float* Tin;
  const float* cw0; const float* cb0; const float* cw1; const float* cb1; const float* cw2; const float* cb2;
  const float* pw0; const float* pb0; const float* pw1; const float* pb1; const float* pw2; const float* pb2;
  const float* fmw1; const float* fmb1; const float* fmw2; const float* fmb2;
  const float* fvw1; const float* fvb1; const float* fvw2; const float* fvb2;
  const float* lw0; const float* lb0; const float* lw1; const float* lb1; const float* lw2; const float* lb2;
  const float* w12src;   // precomputed w12/b12 in d_ws, or nullptr
  float* out;
};

__device__ __forceinline__ const float4* rc4(const float* p) { return reinterpret_cast<const float4*>(p); }
__device__ __forceinline__ float4*       rw4(float* p)       { return reinterpret_cast<float4*>(p); }

__device__ __forceinline__ void load8(const float* __restrict__ src, float* dst) {
  float4 a = rc4(src)[0], b = rc4(src)[1];
  dst[0]=a.x; dst[1]=a.y; dst[2]=a.z; dst[3]=a.w;
  dst[4]=b.x; dst[5]=b.y; dst[6]=b.z; dst[7]=b.w;
}
__device__ __forceinline__ void store8(float* __restrict__ dst, const float* v) {
  rw4(dst)[0] = make_float4(v[0],v[1],v[2],v[3]);
  rw4(dst)[1] = make_float4(v[4],v[5],v[6],v[7]);
}
__device__ __forceinline__ void store16(float* __restrict__ dst, const float* v) {
  rw4(dst)[0] = make_float4(v[0],v[1],v[2],v[3]);
  rw4(dst)[1] = make_float4(v[4],v[5],v[6],v[7]);
  rw4(dst)[2] = make_float4(v[8],v[9],v[10],v[11]);
  rw4(dst)[3] = make_float4(v[12],v[13],v[14],v[15]);
}

union PU { h2 h; uint32_t u; };
union U4 { uint32_t u[4]; h2 h[4]; h8 v; uint4 q; };

__device__ __forceinline__ h2 pack2(float a, float b) {
  h2 r; r[0] = (_Float16)a; r[1] = (_Float16)b; return r;
}

// ---- prep: collapse decoder layers 1+2 (linear compose; no relu between them)
__global__ __launch_bounds__(256) void tld_prep(const float* __restrict__ lw1,
                                                const float* __restrict__ lw2,
                                                const float* __restrict__ lb1,
                                                const float* __restrict__ lb2,
                                                float* __restrict__ ws) {
  const int tid = threadIdx.x;
  #pragma unroll 1
  for (int i = tid; i < 1024; i += 256) {
    int n = i >> 6, h = i & 63;
    float s = 0.f;
    #pragma unroll 8
    for (int o = 0; o < 64; ++o)
      s = fmaf(lw1[n * 4096 + h * 64 + o], lw2[n * 64 + o], s);
    ws[i] = s;
  }
  if (tid < 16) {
    float b = lb2[tid];
    #pragma unroll 8
    for (int o = 0; o < 64; ++o)
      b = fmaf(lb1[tid * 64 + o], lw2[tid * 64 + o], b);
    ws[1024 + tid] = b;
  }
}

__global__ __launch_bounds__(256, 2) void tld_fused(Params p) {
  // ~77.5 KB total -> 2 blocks/CU
  __shared__ __align__(16) float     s_w12[1024];
  __shared__ __align__(16) float     s_b12[16];
  __shared__ __align__(16) float     s_lb0[1024];
  __shared__ __align__(16) float     s_ew2t[128 * 8];     // pw2 transposed: [nk][i]
  __shared__ __align__(16) float     s_eb2b[128];         // pb2
  __shared__ __align__(16) float     s_hw1t[2][1024];     // head W1 transposed [o][f]
  __shared__ __align__(16) float     s_hw2[2][1024];      // head W2 [o][j]
  __shared__ __align__(16) float     s_hb1[2][128];
  __shared__ __align__(16) float     s_hb2[2][8];
  __shared__ __align__(16) _Float16  s_W[2][64 * 40];     // Wt[j][k] f16, row pad 40 (80B)
  __shared__ __align__(16) uint32_t  s_dl[129 * 20];      // latent f16-pairs, row pad 20 u32 (80B)
  __shared__ __align__(16) float     s_e1[128 * 12];      // role1 e1, row pad 12 (48B)
  __shared__ __align__(16) unsigned long long s_msk[128 * 3]; // role0 Ct bits (lo,hi,pad)
  __shared__ __align__(16) float     s_res[4][16 * 68];   // per-wave results [n][t], row pad 68

  const int tid = threadIdx.x;
  const int B   = blockIdx.x * 128;

  // ================= block staging =================
  rw4(s_lb0)[tid]    = rc4(p.lb0)[tid];
  rw4(s_hw2[0])[tid] = rc4(p.fmw2)[tid];
  rw4(s_hw2[1])[tid] = rc4(p.fvw2)[tid];
  if (tid < 32)       { rw4(s_hb1[0])[tid] = rc4(p.fmb1)[tid]; }
  else if (tid < 64)  { rw4(s_hb1[1])[tid - 32] = rc4(p.fvb1)[tid - 32]; }
  else if (tid < 96)  { rw4(s_eb2b)[tid - 64] = rc4(p.pb2)[tid - 64]; }
  else if (tid < 100) { int q = tid - 96; rw4(s_hb2[q >> 1])[q & 1] = rc4((q >> 1) ? p.fvb2 : p.fmb2)[q & 1]; }
  #pragma unroll 1
  for (int i = tid; i < 2048; i += 256) {  // transpose head W1 -> [o][f]
    int r = i >> 10, ii = i & 1023, o = ii >> 3, f = ii & 7;
    s_hw1t[r][ii] = (r ? p.fvw1 : p.fmw1)[f * 128 + o];
  }
  if (tid < 128) {                         // transpose pw2 -> [nk][i]
    #pragma unroll
    for (int i = 0; i < 8; ++i) s_ew2t[tid * 8 + i] = p.pw2[i * 128 + tid];
  }
  if (p.w12src) {
    rw4(s_w12)[tid] = rc4(p.w12src)[tid];
    if (tid < 4) rw4(s_b12)[tid] = rc4(p.w12src + 1024)[tid];
  } else {
    #pragma unroll 1
    for (int i = tid; i < 1024; i += 256) {
      int n = i >> 6, h = i & 63;
      float s = 0.f;
      for (int o = 0; o < 64; ++o)
        s = fmaf(p.lw1[n * 4096 + h * 64 + o], p.lw2[n * 64 + o], s);
      s_w12[i] = s;
    }
    if (tid < 16) {
      float b = p.lb2[tid];
      for (int o = 0; o < 64; ++o)
        b = fmaf(p.lb1[tid * 64 + o], p.lw2[tid * 64 + o], b);
      s_b12[tid] = b;
    }
  }
  // W node 0 -> f16 transposed LDS (thread: k = tid&31, j0 = (tid>>5)*8)
  const int wk  = tid & 31;
  const int wj0 = (tid >> 5) * 8;
  {
    const float4* g = rc4(p.lw0);
    float4 wa = g[wk * 16 + (tid >> 5) * 2];
    float4 wb = g[wk * 16 + (tid >> 5) * 2 + 1];
    _Float16* dW = s_W[0];
    dW[(wj0 + 0) * 40 + wk] = (_Float16)wa.x;
    dW[(wj0 + 1) * 40 + wk] = (_Float16)wa.y;
    dW[(wj0 + 2) * 40 + wk] = (_Float16)wa.z;
    dW[(wj0 + 3) * 40 + wk] = (_Float16)wa.w;
    dW[(wj0 + 4) * 40 + wk] = (_Float16)wb.x;
    dW[(wj0 + 5) * 40 + wk] = (_Float16)wb.y;
    dW[(wj0 + 6) * 40 + wk] = (_Float16)wb.z;
    dW[(wj0 + 7) * 40 + wk] = (_Float16)wb.w;
  }
  __syncthreads();

  // ================= phase 1 (round-4 verified structure) =================
  const int u    = tid & 127;
  const int t    = B + u;
  const int role = __builtin_amdgcn_readfirstlane((int)(tid >> 7));
  const float Tt = p.Tin[t];

  unsigned long long cmlo = 0ull, cmhi = 0ull;
  float e1f[8];

  if (role == 0) {
    // f64 path: <0.1 binarization must match f64-resolved reference (round-1 fail)
    double e0d[8], e1d[8];
    const double Td = (double)Tt;
    #pragma unroll
    for (int j = 0; j < 8; ++j) {
      double v = Td * (double)p.cw0[j] + (double)p.cb0[j];
      e0d[j] = v < 0.0 ? 0.01 * v : v;
    }
    #pragma unroll
    for (int j = 0; j < 8; ++j) {
      double v = (double)p.cb1[j];
      #pragma unroll
      for (int i = 0; i < 8; ++i) v = fma(e0d[i], (double)p.cw1[i * 8 + j], v);
      e1d[j] = v < 0.0 ? 0.01 * v : v;
    }
    #pragma unroll 1
    for (int n2 = 0; n2 < 8; ++n2) {       // node pairs -> full 64B line stores
      float cb[16];
      #pragma unroll
      for (int kk = 0; kk < 16; ++kk) {
        const int nk = n2 * 16 + kk;
        double s = (double)p.cb2[nk];
        #pragma unroll
        for (int i = 0; i < 8; ++i)
          s = fma(e1d[i], (double)p.cw2[i * 128 + nk], s);
        const int b = (s < 0.1) ? 0 : 1;
        cb[kk] = (float)b;
        if (nk < 64) cmlo |= (unsigned long long)b << nk;
        else         cmhi |= (unsigned long long)b << (nk - 64);
      }
      store16(p.out + OFF_CT + (size_t)t * 128 + n2 * 16, cb);
    }
    s_msk[u * 3]     = cmlo;
    s_msk[u * 3 + 1] = cmhi;
  } else {
    float e0[8];
    #pragma unroll
    for (int j = 0; j < 8; ++j) {
      float v = fmaf(Tt, p.pw0[j], p.pb0[j]);
      e0[j] = v < 0.f ? 0.01f * v : v;
    }
    #pragma unroll
    for (int j = 0; j < 8; ++j) {
      float v = p.pb1[j];
      #pragma unroll
      for (int i = 0; i < 8; ++i) v = fmaf(e0[i], p.pw1[i * 8 + j], v);
      e1f[j] = v < 0.f ? 0.01f * v : v;
    }
    // stage e1 for decode c-recompute
    {
      float4* d = (float4*)&s_e1[u * 12];
      d[0] = make_float4(e1f[0], e1f[1], e1f[2], e1f[3]);
      d[1] = make_float4(e1f[4], e1f[5], e1f[6], e1f[7]);
    }
    // Ct_1 compute + full-line stores
    #pragma unroll 1
    for (int n2 = 0; n2 < 8; ++n2) {
      float cb[16];
      #pragma unroll
      for (int kk = 0; kk < 16; ++kk) {
        const int nk = n2 * 16 + kk;
        const float4* w = (const float4*)&s_ew2t[nk * 8];
        float4 x0 = w[0], x1 = w[1];
        float s = s_eb2b[nk];
        s = fmaf(e1f[0], x0.x, s); s = fmaf(e1f[1], x0.y, s);
        s = fmaf(e1f[2], x0.z, s); s = fmaf(e1f[3], x0.w, s);
        s = fmaf(e1f[4], x1.x, s); s = fmaf(e1f[5], x1.y, s);
        s = fmaf(e1f[6], x1.z, s); s = fmaf(e1f[7], x1.w, s);
        cb[kk] = s;
      }
      store16(p.out + OFF_CT1 + (size_t)t * 128 + n2 * 16, cb);
    }
  }

  // ---- latent loads (role0: rows t; role1: rows t-1 / zeros)
  float dl[4][8];
  if (role == 0) {
    load8(p.lm + (size_t)t * 8, dl[0]);
    load8(p.lm + (size_t)TL * 8 + (size_t)t * 8, dl[1]);
    load8(p.lv + (size_t)t * 8, dl[2]);
    load8(p.lv + (size_t)TL * 8 + (size_t)t * 8, dl[3]);
  } else {
    if (t > 0) {
      load8(p.lm + (size_t)(t - 1) * 8, dl[0]);
      load8(p.lm + (size_t)TL * 8 + (size_t)(t - 1) * 8, dl[1]);
      load8(p.lv + (size_t)(t - 1) * 8, dl[2]);
      load8(p.lv + (size_t)TL * 8 + (size_t)(t - 1) * 8, dl[3]);
    } else {
      #pragma unroll
      for (int r = 0; r < 4; ++r)
        #pragma unroll
        for (int j = 0; j < 8; ++j) dl[r][j] = 0.f;
    }
  }
  // stage latent rows as f16 pairs: slot s holds absolute row (B-1+s).
  // role0 thread u owns row B+u -> slot u+1; role1 thread 0 owns row B-1 -> slot 0.
  {
    const int slot = (role == 0) ? (u + 1) : (u == 0 ? 0 : -1);
    if (slot >= 0) {
      uint32_t dw[16];
      #pragma unroll
      for (int k = 0; k < 8; ++k) {
        PU a; a.h = pack2(dl[0][k], dl[1][k]); dw[k]     = a.u;   // lm pair
        PU b; b.h = pack2(dl[2][k], dl[3][k]); dw[8 + k] = b.u;   // lv pair
      }
      uint4* dst = (uint4*)&s_dl[slot * 20];
      dst[0] = make_uint4(dw[0], dw[1], dw[2], dw[3]);
      dst[1] = make_uint4(dw[4], dw[5], dw[6], dw[7]);
      dst[2] = make_uint4(dw[8], dw[9], dw[10], dw[11]);
      dst[3] = make_uint4(dw[12], dw[13], dw[14], dw[15]);
    }
  }

  // ---- heads (unchanged from round 4)
  {
    float hx[2][8];
    if (role == 0) {
      #pragma unroll
      for (int j = 0; j < 8; ++j) { hx[0][j] = dl[0][j]; hx[1][j] = dl[1][j]; }
    } else {
      load8(p.lv + (size_t)t * 8, hx[0]);
      load8(p.lv + (size_t)TL * 8 + (size_t)t * 8, hx[1]);
    }
    float acc8[2][8];
    #pragma unroll
    for (int l = 0; l < 2; ++l)
      #pragma unroll
      for (int j = 0; j < 8; ++j) acc8[l][j] = s_hb2[role][j];
    const float* w1t = s_hw1t[role];
    const float* w2r = s_hw2[role];
    const float* b1  = s_hb1[role];
    #pragma unroll 1
    for (int o = 0; o < 128; ++o) {
      float4 u0 = rc4(w1t)[o * 2], u1 = rc4(w1t)[o * 2 + 1];
      const float wf[8] = {u0.x,u0.y,u0.z,u0.w,u1.x,u1.y,u1.z,u1.w};
      const float bo = b1[o];
      float a0 = bo, a1 = bo;
      #pragma unroll
      for (int f = 0; f < 8; ++f) {
        a0 = fmaf(hx[0][f], wf[f], a0);
        a1 = fmaf(hx[1][f], wf[f], a1);
      }
      a0 = fmaxf(a0, 0.f); a1 = fmaxf(a1, 0.f);
      float4 v0 = rc4(w2r)[o * 2], v1 = rc4(w2r)[o * 2 + 1];
      const float w2f[8] = {v0.x,v0.y,v0.z,v0.w,v1.x,v1.y,v1.z,v1.w};
      #pragma unroll
      for (int j = 0; j < 8; ++j) {
        acc8[0][j] = fmaf(a0, w2f[j], acc8[0][j]);
        acc8[1][j] = fmaf(a1, w2f[j], acc8[1][j]);
      }
    }
    const size_t hbase = role ? OFF_LVP : OFF_LMP;
    store8(p.out + hbase + (size_t)t * 8, acc8[0]);
    store8(p.out + hbase + (size_t)TL * 8 + (size_t)t * 8, acc8[1]);
  }

  __syncthreads();   // dl / e1 / msk staged; W[0] staged

  // ================= decode: per-node f16 MFMA =================
  // wave w: drole = w>>1; t_local range = (w&1)*64 .. +63
  // MFMA 16x16x32_f16: A[i][k]: i=lane&15 (=t), k=(lane>>4)*8+e
  //                    B[k][j]: j=lane&15, k=(lane>>4)*8+e
  //                    D: col(j)=lane&15, row(t)=(lane>>4)*4+reg  [m89-verified]
  const int w     = tid >> 6;
  const int lane  = tid & 63;
  const int drole = __builtin_amdgcn_readfirstlane(w >> 1);
  const int tl0   = (w & 1) * 64;
  const int l15   = lane & 15;
  const int g     = lane >> 4;
  const int kb    = (g & 1) * 4;          // c-index base for this lane's k-slab
  float* res = s_res[w];

  #pragma unroll 1
  for (int n = 0; n < 16; ++n) {
    // T14: issue next node's weights early
    float4 wa, wb;
    if (n < 15) {
      const float4* gsrc = rc4(p.lw0 + (size_t)(n + 1) * 2048);
      wa = gsrc[wk * 16 + (tid >> 5) * 2];
      wb = gsrc[wk * 16 + (tid >> 5) * 2 + 1];
    }
    // role1: hoist c-weights (ew2t rows nk = n*8+kb+q) into regs
    float cwv[4][8];
    if (drole == 1) {
      #pragma unroll
      for (int q = 0; q < 4; ++q) {
        const float4* ww = (const float4*)&s_ew2t[(n * 8 + kb + q) * 8];
        float4 x0 = ww[0], x1 = ww[1];
        cwv[q][0]=x0.x; cwv[q][1]=x0.y; cwv[q][2]=x0.z; cwv[q][3]=x0.w;
        cwv[q][4]=x1.x; cwv[q][5]=x1.y; cwv[q][6]=x1.z; cwv[q][7]=x1.w;
      }
    }
    // B fragments + per-j constants
    const _Float16* Wcur = s_W[n & 1];
    h8 Bf[4];
    float bias[4], w12v[4];
    #pragma unroll
    for (int ji = 0; ji < 4; ++ji) {
      Bf[ji]   = *(const h8*)&Wcur[(ji * 16 + l15) * 40 + g * 8];
      bias[ji] = s_lb0[n * 64 + ji * 16 + l15];
      w12v[ji] = s_w12[n * 64 + ji * 16 + l15];
    }
    // A fragments (one per 16-t tile)
    h8 Af[4];
    #pragma unroll
    for (int ti = 0; ti < 4; ++ti) {
      const int tloc = tl0 + ti * 16 + l15;
      const int slot = tloc + 1 - drole;
      U4 dv; dv.q = *(const uint4*)&s_dl[slot * 20 + g * 4];
      U4 xf;
      if (drole == 0) {
        const unsigned long long m = s_msk[tloc * 3 + (n >> 3)];
        const unsigned byte = (unsigned)(m >> ((n & 7) * 8)) & 0xffu;
        #pragma unroll
        for (int q = 0; q < 4; ++q)
          xf.u[q] = ((byte >> (kb + q)) & 1u) ? dv.u[q] : 0u;
      } else {
        const float4* e = (const float4*)&s_e1[tloc * 12];
        float4 e0 = e[0], e1v = e[1];
        const float ef[8] = {e0.x,e0.y,e0.z,e0.w,e1v.x,e1v.y,e1v.z,e1v.w};
        #pragma unroll
        for (int q = 0; q < 4; ++q) {
          float c = s_eb2b[n * 8 + kb + q];
          #pragma unroll
          for (int i = 0; i < 8; ++i) c = fmaf(ef[i], cwv[q][i], c);
          xf.h[q] = pack2(c, c) * dv.h[q];
        }
      }
      Af[ti] = xf.v;
    }
    // MFMA + epilogue per t-tile
    const float b12n = s_b12[n];
    #pragma unroll
    for (int ti = 0; ti < 4; ++ti) {
      f32x4 d0, d1, d2, d3;
      d0[0]=bias[0]; d0[1]=bias[0]; d0[2]=bias[0]; d0[3]=bias[0];
      d1[0]=bias[1]; d1[1]=bias[1]; d1[2]=bias[1]; d1[3]=bias[1];
      d2[0]=bias[2]; d2[1]=bias[2]; d2[2]=bias[2]; d2[3]=bias[2];
      d3[0]=bias[3]; d3[1]=bias[3]; d3[2]=bias[3]; d3[3]=bias[3];
      d0 = __builtin_amdgcn_mfma_f32_16x16x32_f16(Af[ti], Bf[0], d0, 0, 0, 0);
      d1 = __builtin_amdgcn_mfma_f32_16x16x32_f16(Af[ti], Bf[1], d1, 0, 0, 0);
      d2 = __builtin_amdgcn_mfma_f32_16x16x32_f16(Af[ti], Bf[2], d2, 0, 0, 0);
      d3 = __builtin_amdgcn_mfma_f32_16x16x32_f16(Af[ti], Bf[3], d3, 0, 0, 0);
      float pr[4];
      #pragma unroll
      for (int reg = 0; reg < 4; ++reg) {
        float s = fmaxf(d0[reg], 0.f) * w12v[0];
        s = fmaf(fmaxf(d1[reg], 0.f), w12v[1], s);
        s = fmaf(fmaxf(d2[reg], 0.f), w12v[2], s);
        s = fmaf(fmaxf(d3[reg], 0.f), w12v[3], s);
        pr[reg] = s;
      }
      // butterfly over the 16-lane group (j dimension)
      #pragma unroll
      for (int m = 1; m < 16; m <<= 1) {
        #pragma unroll
        for (int reg = 0; reg < 4; ++reg)
          pr[reg] += __shfl_xor(pr[reg], m, 64);
      }
      #pragma unroll
      for (int reg = 0; reg < 4; ++reg)
        pr[reg] = fmaxf(b12n + pr[reg], 0.f);
      if (l15 == 0) {
        float4* d = (float4*)&res[n * 68 + ti * 16 + g * 4];
        d[0] = make_float4(pr[0], pr[1], pr[2], pr[3]);
      }
    }
    // stage next node's weights (after all reads of buffer (n+1)&1 finished last iter)
    if (n < 15) {
      _Float16* dW = s_W[(n + 1) & 1];
      dW[(wj0 + 0) * 40 + wk] = (_Float16)wa.x;
      dW[(wj0 + 1) * 40 + wk] = (_Float16)wa.y;
      dW[(wj0 + 2) * 40 + wk] = (_Float16)wa.z;
      dW[(wj0 + 3) * 40 + wk] = (_Float16)wa.w;
      dW[(wj0 + 4) * 40 + wk] = (_Float16)wb.x;
      dW[(wj0 + 5) * 40 + wk] = (_Float16)wb.y;
      dW[(wj0 + 6) * 40 + wk] = (_Float16)wb.z;
      dW[(wj0 + 7) * 40 + wk] = (_Float16)wb.w;
    }
    __syncthreads();
  }

  // final store: lane tl owns t = B + tl0 + lane, reads its 16 node results
  {
    float o16[16];
    #pragma unroll
    for (int n = 0; n < 16; ++n) o16[n] = res[n * 68 + lane];
    const size_t r_off = drole ? OFF_PRED : OFF_RECON;
    store16(p.out + r_off + (size_t)(B + tl0 + lane) * 16, o16);
  }
}

extern "C" void kernel_launch(void* const* d_in, const int* in_sizes, int n_in,
                              void* d_out, int out_size, void* d_ws, size_t ws_size,
                              hipStream_t stream) {
  Params p;
  p.lm   = (const float*)d_in[0];
  p.lv   = (const float*)d_in[1];
  p.Tin  = (const float*)d_in[2];
  p.cw0  = (const float*)d_in[3];  p.cb0 = (const float*)d_in[4];
  p.cw1  = (const float*)d_in[5];  p.cb1 = (const float*)d_in[6];
  p.cw2  = (const float*)d_in[7];  p.cb2 = (const float*)d_in[8];
  p.pw0  = (const float*)d_in[9];  p.pb0 = (const float*)d_in[10];
  p.pw1  = (const float*)d_in[11]; p.pb1 = (const float*)d_in[12];
  p.pw2  = (const float*)d_in[13]; p.pb2 = (const float*)d_in[14];
  p.fmw1 = (const float*)d_in[15]; p.fmb1 = (const float*)d_in[16];
  p.fmw2 = (const float*)d_in[17]; p.fmb2 = (const float*)d_in[18];
  p.fvw1 = (const float*)d_in[19]; p.fvb1 = (const float*)d_in[20];
  p.fvw2 = (const float*)d_in[21]; p.fvb2 = (const float*)d_in[22];
  p.lw0  = (const float*)d_in[23]; p.lb0 = (const float*)d_in[24];
  p.lw1  = (const float*)d_in[25]; p.lb1 = (const float*)d_in[26];
  p.lw2  = (const float*)d_in[27]; p.lb2 = (const float*)d_in[28];
  p.out  = (float*)d_out;

  const bool use_ws = ws_size >= 1040 * sizeof(float);
  if (use_ws) {
    tld_prep<<<dim3(1), dim3(256), 0, stream>>>(p.lw1, p.lw2, p.lb1, p.lb2, (float*)d_ws);
    p.w12src = (const float*)d_ws;
  } else {
    p.w12src = nullptr;
  }
  tld_fused<<<dim3(TL / 128), dim3(256), 0, stream>>>(p);
}